// Round 8
// baseline (2243.917 us; speedup 1.0000x reference)
//
#include <hip/hip_runtime.h>
#include <cstdint>

#define EPSF 1e-6f

// ---------------- problem constants (fixed by setup_inputs) ----------------
constexpr int B = 8, N = 3136, N0 = 12544, CIN = 64, COUT = 128;
constexpr int H = 112, W = 112, HW = H * W;
constexpr int HO = 56, WO = 56, OHW = HO * WO;
constexpr int NS = 784;

// ---------------- workspace layout (bytes) ----------------
constexpr size_t o_xmap = 0;
constexpr size_t sz_xmap = (size_t)B * HW * CIN * 4;
constexpr size_t o_cnt  = o_xmap + sz_xmap;
constexpr size_t sz_cnt = (size_t)B * HW * 4;
constexpr size_t o_wsum = o_cnt + sz_cnt;
constexpr size_t sz_wsum = (size_t)B * N * 4;
constexpr size_t o_maxw = o_wsum + sz_wsum;
constexpr size_t sz_maxw = 32;
constexpr size_t o_zpad = o_maxw + sz_maxw;
constexpr size_t sz_zpad = 256;
constexpr size_t zero_end = o_zpad + sz_zpad;
constexpr size_t o_wt   = (zero_end + 255) & ~(size_t)255;
constexpr size_t o_swt  = o_wt + 576 * 128 * 4;
constexpr size_t o_pixf = o_swt + 64 * 128 * 4;
constexpr size_t o_conv = o_pixf + (size_t)B * N0 * 4;
constexpr size_t o_xnew = o_conv + (size_t)B * OHW * 128 * 4;
constexpr size_t o_sqn  = o_xnew + (size_t)B * N * 128 * 4;
constexpr size_t o_normw = o_sqn + (size_t)B * N * 4;
constexpr size_t o_idxt = o_normw + (size_t)B * N * 4;
constexpr size_t o_d2   = (o_idxt + (size_t)B * N * 4 + 255) & ~(size_t)255;
constexpr size_t D2B = (size_t)N * N * 4;

// order-isomorphic float->uint key: a<b (float) <=> tkey(a)<tkey(b) (uint)
__device__ inline unsigned tkey(float v) {
    unsigned u = __float_as_uint(v);
    unsigned m = (unsigned)((int)u >> 31);
    return u ^ (m | 0x80000000u);
}

// ---------------- weight transpose ----------------
__global__ void k_transpose(const float* __restrict__ conv_w, const float* __restrict__ skip_w,
                            float* __restrict__ wT, float* __restrict__ swt) {
    int g = blockIdx.x * 256 + threadIdx.x;
    if (g < 576 * 128) {
        int k = g >> 7, co = g & 127;
        int kpos = k >> 6, ci = k & 63;
        wT[g] = conv_w[(co * 64 + ci) * 9 + kpos];
    } else {
        int g2 = g - 576 * 128;
        if (g2 < 64 * 128) {
            int ci = g2 >> 7, co = g2 & 127;
            swt[g2] = skip_w[co * 64 + ci];
        }
    }
}

// ---------------- pixel index @112 + count ----------------
__global__ void k_pix_cnt(const float* __restrict__ loc, int* __restrict__ pixf,
                          float* __restrict__ cnt) {
    int g = blockIdx.x * 256 + threadIdx.x;
    if (g >= B * N0) return;
    int b = g / N0;
    float lx = loc[2 * g], ly = loc[2 * g + 1];
    lx = fminf(fmaxf(lx, -1.f), 1.f);
    ly = fminf(fmaxf(ly, -1.f), 1.f);
    int px = (int)rintf((lx + 1.f) * 0.5f * 111.f); px = min(max(px, 0), 111);
    int py = (int)rintf((ly + 1.f) * 0.5f * 111.f); py = min(max(py, 0), 111);
    int pf = b * HW + py * W + px;
    pixf[g] = pf;
    atomicAdd(&cnt[pf], 1.f);
}

// ---------------- token2map scatter ----------------
__global__ void k_token2map(const float* __restrict__ x, const int* __restrict__ idx_agg,
                            const int* __restrict__ pixf, const float* __restrict__ cnt,
                            float* __restrict__ xmap) {
    int t = blockIdx.x * 256 + threadIdx.x;
    int g = t >> 6, c = t & 63;
    if (g >= B * N0) return;
    int pf = pixf[g];
    float val = 1.f / (cnt[pf] + EPSF);
    int b = g / N0;
    int tok = idx_agg[g];
    float xv = x[((size_t)(b * N + tok)) * 64 + c];
    atomicAdd(&xmap[(size_t)pf * 64 + c], xv * val);
}

// ---------------- 3x3 stride-2 conv (NHWC, direct) ----------------
__global__ __launch_bounds__(128) void k_conv(const float* __restrict__ xmap,
                                              const float* __restrict__ wT,
                                              const float* __restrict__ cb,
                                              const float* __restrict__ zpad,
                                              float* __restrict__ conv_out) {
    int co = threadIdx.x;
    int wo0 = blockIdx.x * 8, ho = blockIdx.y, b = blockIdx.z;
    float acc[8];
    float bias = cb[co];
#pragma unroll
    for (int p = 0; p < 8; p++) acc[p] = bias;
    for (int kh = 0; kh < 3; ++kh) {
        int iy = 2 * ho + kh - 1;
        bool vy = (iy >= 0 && iy < H);
        for (int kw = 0; kw < 3; ++kw) {
            const float* wp = wT + (size_t)((kh * 3 + kw) * 64) * 128 + co;
            const float* bp[8];
#pragma unroll
            for (int p = 0; p < 8; p++) {
                int ix = 2 * (wo0 + p) + kw - 1;
                bool v = vy && ix >= 0 && ix < W;
                bp[p] = v ? (xmap + ((size_t)b * HW + iy * W + ix) * 64) : zpad;
            }
#pragma unroll 4
            for (int ci = 0; ci < 64; ++ci) {
                float wv = wp[(size_t)ci * 128];
#pragma unroll
                for (int p = 0; p < 8; p++) acc[p] = fmaf(bp[p][ci], wv, acc[p]);
            }
        }
    }
    size_t ob = ((size_t)b * OHW + ho * WO + wo0) * 128 + co;
#pragma unroll
    for (int p = 0; p < 8; p++) conv_out[ob + (size_t)p * 128] = acc[p];
}

// ---------------- wsum scatter ----------------
__global__ void k_wsum(const int* __restrict__ idx_agg, const float* __restrict__ aggw,
                       float* __restrict__ wsum) {
    int g = blockIdx.x * 256 + threadIdx.x;
    if (g >= B * N0) return;
    int b = g / N0;
    atomicAdd(&wsum[(size_t)b * N + idx_agg[g]], aggw[g]);
}

// ---------------- skip GEMM ----------------
__global__ void k_skip(const float* __restrict__ x, const float* __restrict__ swt,
                       float* __restrict__ xnew) {
    int t = blockIdx.x * 256 + threadIdx.x;
    int g = t >> 7, co = t & 127;
    const float* xr = x + (size_t)g * 64;
    float acc = 0.f;
#pragma unroll 8
    for (int ci = 0; ci < 64; ++ci) acc = fmaf(xr[ci], swt[ci * 128 + co], acc);
    xnew[t] = acc;
}

// ---------------- map2token scatter ----------------
__global__ void k_map2token(const float* __restrict__ loc, const int* __restrict__ idx_agg,
                            const float* __restrict__ aggw, const float* __restrict__ wsum,
                            const float* __restrict__ conv_out, float* __restrict__ xnew) {
    int t = blockIdx.x * 256 + threadIdx.x;
    int g = t >> 7, co = t & 127;
    if (g >= B * N0) return;
    int b = g / N0;
    float lx = loc[2 * g], ly = loc[2 * g + 1];
    lx = fminf(fmaxf(lx, -1.f), 1.f);
    ly = fminf(fmaxf(ly, -1.f), 1.f);
    int px = (int)rintf((lx + 1.f) * 0.5f * 55.f); px = min(max(px, 0), 55);
    int py = (int)rintf((ly + 1.f) * 0.5f * 55.f); py = min(max(py, 0), 55);
    int opix = py * WO + px;
    int tok = idx_agg[g];
    float val = aggw[g] / (wsum[(size_t)b * N + tok] + EPSF);
    float feat = conv_out[((size_t)b * OHW + opix) * 128 + co];
    atomicAdd(&xnew[((size_t)b * N + tok) * 128 + co], feat * val);
}

// ---------------- squared norms ----------------
__global__ void k_sqn(const float* __restrict__ xnew, float* __restrict__ sqn) {
    int tid = threadIdx.x;
    int wid = tid >> 6, lane = tid & 63;
    int row = blockIdx.x * 4 + wid;
    const float* xr = xnew + (size_t)row * 128;
    float2 v = *(const float2*)(xr + lane * 2);
    float s = v.x * v.x + v.y * v.y;
#pragma unroll
    for (int off = 32; off > 0; off >>= 1) s += __shfl_xor(s, off, 64);
    if (lane == 0) sqn[row] = s;
}

// ---------------- D2 GEMM (symmetric): compute by<=bx tiles, mirror-store ----------------
// D2[i][j] == D2[j][i] bit-exactly: fmaf chain is arg-symmetric, sqa+sb-2acc commutes.
__global__ __launch_bounds__(256) void k_d2gemm(const float* __restrict__ xnew,
                                                const float* __restrict__ sqn,
                                                unsigned* __restrict__ d2, int b_off) {
    int bx = blockIdx.x, by = blockIdx.y, cb = blockIdx.z;
    if (by > bx) return;   // lower-triangle tiles produced by mirror store
    __shared__ float As[64 * 132];
    __shared__ float Bs[64 * 132];
    int tid = threadIdx.x;
    int tx = tid & 15, ty = tid >> 4;
    int b = b_off + cb;
    int ri0 = by * 64, rj0 = bx * 64;
    const float* xb = xnew + (size_t)b * N * 128;
#pragma unroll
    for (int q = 0; q < 8; q++) {
        int f4 = tid + q * 256;
        int r = f4 >> 5, k4 = (f4 & 31) << 2;
        *(float4*)&As[r * 132 + k4] = *(const float4*)(xb + (size_t)(ri0 + r) * 128 + k4);
        *(float4*)&Bs[r * 132 + k4] = *(const float4*)(xb + (size_t)(rj0 + r) * 128 + k4);
    }
    __syncthreads();
    float acc[4][4] = {};
    const float* Ap = As + (ty * 4) * 132;
    const float* Bp = Bs + (tx * 4) * 132;
    for (int kk = 0; kk < 32; ++kk) {
        int k = kk * 4;
        float4 a[4], bb[4];
#pragma unroll
        for (int u = 0; u < 4; u++) a[u] = *(const float4*)(Ap + u * 132 + k);
#pragma unroll
        for (int v = 0; v < 4; v++) bb[v] = *(const float4*)(Bp + v * 132 + k);
#pragma unroll
        for (int u = 0; u < 4; u++)
#pragma unroll
            for (int v = 0; v < 4; v++) {
                acc[u][v] = fmaf(a[u].x, bb[v].x, acc[u][v]);
                acc[u][v] = fmaf(a[u].y, bb[v].y, acc[u][v]);
                acc[u][v] = fmaf(a[u].z, bb[v].z, acc[u][v]);
                acc[u][v] = fmaf(a[u].w, bb[v].w, acc[u][v]);
            }
    }
    const float* sq = sqn + (size_t)b * N;
    float4 sb = *(const float4*)(sq + rj0 + tx * 4);
    unsigned* d2c = d2 + (size_t)cb * N * N;
    unsigned okey[4][4];
#pragma unroll
    for (int u = 0; u < 4; u++) {
        int rowg = ri0 + ty * 4 + u;
        float sqa = sq[rowg];
        uint4 o;
        o.x = tkey(sqa + sb.x - 2.f * acc[u][0]);
        o.y = tkey(sqa + sb.y - 2.f * acc[u][1]);
        o.z = tkey(sqa + sb.z - 2.f * acc[u][2]);
        o.w = tkey(sqa + sb.w - 2.f * acc[u][3]);
        okey[u][0] = o.x; okey[u][1] = o.y; okey[u][2] = o.z; okey[u][3] = o.w;
        *(uint4*)(d2c + (size_t)rowg * N + rj0 + tx * 4) = o;
    }
    if (bx != by) {
        // mirror tile: row' = rj0+tx*4+v, cols' = ri0+ty*4+(0..3) -> one uint4 per v
#pragma unroll
        for (int v = 0; v < 4; v++) {
            int colg = rj0 + tx * 4 + v;
            uint4 m = make_uint4(okey[0][v], okey[1][v], okey[2][v], okey[3][v]);
            *(uint4*)(d2c + (size_t)colg * N + ri0 + ty * 4) = m;
        }
    }
}

// ---------------- u64 helpers ----------------
template <int CTRL, int RMASK>
__device__ __forceinline__ unsigned long long dppmax64(unsigned long long k) {
    unsigned lo = (unsigned)k, hi = (unsigned)(k >> 32);
    unsigned slo = (unsigned)__builtin_amdgcn_update_dpp((int)lo, (int)lo, CTRL, RMASK, 0xF, false);
    unsigned shi = (unsigned)__builtin_amdgcn_update_dpp((int)hi, (int)hi, CTRL, RMASK, 0xF, false);
    unsigned long long o = ((unsigned long long)shi << 32) | slo;
    return o > k ? o : k;
}
__device__ __forceinline__ unsigned long long rdlane64(unsigned long long k, int l) {
    unsigned lo = (unsigned)__builtin_amdgcn_readlane((int)(unsigned)k, l);
    unsigned hi = (unsigned)__builtin_amdgcn_readlane((int)(k >> 32), l);
    return ((unsigned long long)hi << 32) | lo;
}

// ---------------- FPS v7: fps6 + runner-up register prefetch ----------------
__global__ __launch_bounds__(256) void k_fps7(const unsigned* __restrict__ d2,
                                              int* __restrict__ idx_t,
                                              float* __restrict__ normw, int b_off) {
    int tid = threadIdx.x;
    int lane = tid & 63, wid = tid >> 6;
    int b = b_off + blockIdx.x;
    const unsigned* D2b = d2 + (size_t)blockIdx.x * (size_t)N * N;
    __shared__ unsigned long long slot[2][4];
    __shared__ int cent_l[NS];
    __shared__ int it_l[N];
    __shared__ float cntw[NS];
    const bool full = (tid < 16);
    const unsigned KI = tkey(1e10f);
    unsigned kd[16];
    int am[16];
#pragma unroll
    for (int r = 0; r < 4; r++)
#pragma unroll
        for (int c = 0; c < 4; c++) { kd[r * 4 + c] = (r < 3 || full) ? KI : 0u; am[r * 4 + c] = 0; }

    int far = 0, far2 = -1;
    uint4 p0 = make_uint4(0, 0, 0, 0), p1 = p0, p2 = p0, p3 = p0;

    for (int s = 0; s < NS; ++s) {
        if (tid == 0) cent_l[s] = far;
        uint4 v0, v1, v2, v3;
        if (far == far2) {
            // prefetch hit: row already in registers (d2 immutable -> trivially valid)
            v0 = p0; v1 = p1; v2 = p2; v3 = p3;
        } else {
            const unsigned* row = D2b + (size_t)far * N;
            v0 = *(const uint4*)(row + tid * 4);
            v1 = *(const uint4*)(row + 1024 + tid * 4);
            v2 = *(const uint4*)(row + 2048 + tid * 4);
            v3 = full ? *(const uint4*)(row + 3072 + tid * 4) : make_uint4(0, 0, 0, 0);
        }
        // min-update + merge argmin (strict < -> first-s wins ties)
        uint4 vv[4] = {v0, v1, v2, v3};
#pragma unroll
        for (int r = 0; r < 4; r++) {
            unsigned e[4] = {vv[r].x, vv[r].y, vv[r].z, vv[r].w};
#pragma unroll
            for (int c = 0; c < 4; c++)
                if (e[c] < kd[r * 4 + c]) { kd[r * 4 + c] = e[c]; am[r * 4 + c] = s; }
        }
        if (s == NS - 1) break;   // last row updates assignments only
        // per-thread max of kd
        unsigned tmax = kd[0];
#pragma unroll
        for (int q = 1; q < 16; q++) tmax = max(tmax, kd[q]);
        // per-thread smallest global index achieving tmax
        unsigned il = 4095u;
#pragma unroll
        for (int r = 3; r >= 0; --r)
#pragma unroll
            for (int c = 3; c >= 0; --c)
                if (kd[r * 4 + c] == tmax) il = (unsigned)(r * 1024 + tid * 4 + c);
        unsigned long long key = ((unsigned long long)tmax << 12) | (unsigned long long)(4095u - il);
        // wave max via DPP (pure VALU)
        key = dppmax64<0xB1, 0xF>(key);    // quad_perm [1,0,3,2]
        key = dppmax64<0x4E, 0xF>(key);    // quad_perm [2,3,0,1]
        key = dppmax64<0x141, 0xF>(key);   // row_half_mirror
        key = dppmax64<0x140, 0xF>(key);   // row_mirror
        key = dppmax64<0x142, 0xA>(key);   // row_bcast15 -> rows 1,3
        key = dppmax64<0x143, 0xC>(key);   // row_bcast31 -> rows 2,3 ; lane63 = wave max
        unsigned long long wmax = rdlane64(key, 63);
        int cur = s & 1;
        if (lane == 0) slot[cur][wid] = wmax;
        // raw barrier: LDS visibility only — prefetch vmem stays in flight
        asm volatile("s_waitcnt lgkmcnt(0)\n\ts_barrier" ::: "memory");
        unsigned long long s0 = slot[cur][0], s1 = slot[cur][1];
        unsigned long long s2 = slot[cur][2], s3 = slot[cur][3];
        unsigned long long m0 = s0 > s1 ? s0 : s1, q0 = s0 > s1 ? s1 : s0;
        unsigned long long m1 = s2 > s3 ? s2 : s3, q1 = s2 > s3 ? s3 : s2;
        unsigned long long win, run;
        if (m0 >= m1) { win = m0; run = q0 > m1 ? q0 : m1; }
        else          { win = m1; run = q1 > m0 ? q1 : m0; }
        far = 4095 - (int)(win & 0xFFFull);
        far2 = 4095 - (int)(run & 0xFFFull);
        // speculative prefetch of runner-up row (consumed next iter on hit)
        const unsigned* prow = D2b + (size_t)far2 * N;
        p0 = *(const uint4*)(prow + tid * 4);
        p1 = *(const uint4*)(prow + 1024 + tid * 4);
        p2 = *(const uint4*)(prow + 2048 + tid * 4);
        p3 = full ? *(const uint4*)(prow + 3072 + tid * 4) : make_uint4(0, 0, 0, 0);
    }
    // ---------------- epilogue ----------------
    __syncthreads();
#pragma unroll
    for (int r = 0; r < 4; r++) {
        if (r == 3 && !full) break;
        int i0 = r * 1024 + tid * 4;
        *(int4*)&it_l[i0] = make_int4(am[r * 4 + 0], am[r * 4 + 1], am[r * 4 + 2], am[r * 4 + 3]);
    }
    for (int t = tid; t < NS; t += 256) cntw[t] = 0.f;
    __syncthreads();
    for (int t = tid; t < NS; t += 256) it_l[cent_l[t]] = t;   // centroid -> itself
    __syncthreads();
    for (int i = tid; i < N; i += 256) atomicAdd(&cntw[it_l[i]], 1.f);
    __syncthreads();
    int* it = idx_t + (size_t)b * N;
    float* nw = normw + (size_t)b * N;
    for (int i = tid; i < N; i += 256) {
        int t = it_l[i];
        it[i] = t;
        nw[i] = 1.f / (cntw[t] + EPSF);
    }
}

// ---------------- fallback FPS (no-D2 path) ----------------
__device__ inline unsigned long long packkey(float v, unsigned i) {
    unsigned u = __float_as_uint(v);
    u = (u & 0x80000000u) ? ~u : (u | 0x80000000u);
    return ((unsigned long long)u << 32) | (unsigned long long)(0xFFFFFFFFu - i);
}

__global__ __launch_bounds__(1024) void k_fps0(const float* __restrict__ xnew,
                                               const float* __restrict__ sqn,
                                               int* __restrict__ idx_t,
                                               float* __restrict__ normw, int b_off) {
    int tid = threadIdx.x;
    int b = b_off + blockIdx.x;
    __shared__ unsigned long long slot[2];
    __shared__ int cent[NS];
    __shared__ float cntw[NS];
    __shared__ float csh[128];
    if (tid == 0) { slot[0] = 0ull; slot[1] = 0ull; }
    if (tid < NS) cntw[tid] = 0.f;
    float dist[4] = {1e10f, 1e10f, 1e10f, 1e10f};
    int amin[4] = {0, 0, 0, 0};
    float sqi[4];
#pragma unroll
    for (int r = 0; r < 4; r++) {
        int i = tid + r * 1024;
        if (i < N) sqi[r] = sqn[(size_t)b * N + i];
    }
    __syncthreads();
    int far = 0;
    for (int s = 0; s < NS; ++s) {
        int cur = s & 1;
        if (tid == 0) { cent[s] = far; slot[cur ^ 1] = 0ull; }
        if (tid < 128) csh[tid] = xnew[((size_t)b * N + far) * 128 + tid];
        float sqf = sqn[(size_t)b * N + far];
        __syncthreads();
        unsigned long long key = 0ull;
#pragma unroll
        for (int r = 0; r < 4; r++) {
            int i = tid + r * 1024;
            if (i < N) {
                const float* xr = xnew + ((size_t)b * N + i) * 128;
                float dot = 0.f;
#pragma unroll 8
                for (int k = 0; k < 128; k++) dot = fmaf(xr[k], csh[k], dot);
                float d = sqi[r] + sqf - 2.f * dot;
                if (d < dist[r]) { dist[r] = d; amin[r] = s; }
                unsigned long long k2 = packkey(dist[r], (unsigned)i);
                if (k2 > key) key = k2;
            }
        }
#pragma unroll
        for (int off = 32; off > 0; off >>= 1) {
            unsigned long long o = __shfl_xor(key, off, 64);
            if (o > key) key = o;
        }
        if ((tid & 63) == 0) atomicMax(&slot[cur], key);
        __syncthreads();
        unsigned long long kk = slot[cur];
        far = (int)(0xFFFFFFFFu - (unsigned)(kk & 0xFFFFFFFFull));
        __syncthreads();
    }
    int* it = idx_t + (size_t)b * N;
#pragma unroll
    for (int r = 0; r < 4; r++) { int i = tid + r * 1024; if (i < N) it[i] = amin[r]; }
    __syncthreads();
    if (tid < NS) it[cent[tid]] = tid;
    __syncthreads();
#pragma unroll
    for (int r = 0; r < 4; r++) { int i = tid + r * 1024; if (i < N) atomicAdd(&cntw[it[i]], 1.f); }
    __syncthreads();
    float* nw = normw + (size_t)b * N;
#pragma unroll
    for (int r = 0; r < 4; r++) {
        int i = tid + r * 1024;
        if (i < N) nw[i] = 1.f / (cntw[it[i]] + EPSF);
    }
}

// ---------------- merged-token scatter into out0 ----------------
__global__ void k_merge_scatter(const float* __restrict__ xnew, const int* __restrict__ idx_t,
                                const float* __restrict__ normw, float* __restrict__ out0) {
    int t = blockIdx.x * 256 + threadIdx.x;
    int g = t >> 7, co = t & 127;
    if (g >= B * N) return;
    int b = g / N;
    int s = idx_t[g];
    float nwv = normw[g];
    atomicAdd(&out0[((size_t)b * NS + s) * 128 + co], xnew[(size_t)g * 128 + co] * nwv);
}

// ---------------- outputs 1 & 2 (hierarchical max) ----------------
__global__ void k_out12(const int* __restrict__ idx_agg, const float* __restrict__ aggw,
                        const int* __restrict__ idx_t, const float* __restrict__ normw,
                        float* __restrict__ out1, float* __restrict__ out2,
                        unsigned* __restrict__ maxw) {
    int tid = threadIdx.x;
    int q = blockIdx.x * 256 + tid;
    int b = q / N0;
    int tok = idx_agg[q];
    int it = idx_t[(size_t)b * N + tok];
    out1[q] = (float)it;
    float aw = aggw[q] * normw[(size_t)b * N + tok];
    out2[q] = aw;
    float m = aw;
#pragma unroll
    for (int off = 32; off > 0; off >>= 1) m = fmaxf(m, __shfl_xor(m, off, 64));
    __shared__ float wmax[4];
    int lane = tid & 63, wid = tid >> 6;
    if (lane == 0) wmax[wid] = m;
    __syncthreads();
    if (tid == 0) {
        float mm = fmaxf(fmaxf(wmax[0], wmax[1]), fmaxf(wmax[2], wmax[3]));
        atomicMax(&maxw[b], __float_as_uint(mm));
    }
}

__global__ void k_out2div(float* __restrict__ out2, const unsigned* __restrict__ maxw) {
    int q = blockIdx.x * 256 + threadIdx.x;
    if (q >= B * N0) return;
    int b = q / N0;
    out2[q] = out2[q] / __uint_as_float(maxw[b]);
}

// ---------------- launcher ----------------
extern "C" void kernel_launch(void* const* d_in, const int* in_sizes, int n_in,
                              void* d_out, int out_size, void* d_ws, size_t ws_size,
                              hipStream_t stream) {
    const float* x = (const float*)d_in[0];
    const float* loc = (const float*)d_in[1];
    const int* idx_agg = (const int*)d_in[2];
    const float* aggw = (const float*)d_in[3];
    const float* conv_w = (const float*)d_in[4];
    const float* conv_b = (const float*)d_in[5];
    const float* skip_w = (const float*)d_in[6];

    char* ws = (char*)d_ws;
    float* xmap = (float*)(ws + o_xmap);
    float* cnt = (float*)(ws + o_cnt);
    float* wsum = (float*)(ws + o_wsum);
    unsigned* maxw = (unsigned*)(ws + o_maxw);
    float* zpad = (float*)(ws + o_zpad);
    float* wT = (float*)(ws + o_wt);
    float* swt = (float*)(ws + o_swt);
    int* pixf = (int*)(ws + o_pixf);
    float* conv_out = (float*)(ws + o_conv);
    float* xnew = (float*)(ws + o_xnew);
    float* sqn = (float*)(ws + o_sqn);
    float* normw = (float*)(ws + o_normw);
    int* idx_t = (int*)(ws + o_idxt);
    unsigned* d2 = (unsigned*)(ws + o_d2);

    float* out0 = (float*)d_out;
    float* out1 = out0 + (size_t)B * NS * COUT;
    float* out2 = out1 + (size_t)B * N0;

    hipMemsetAsync(d_ws, 0, zero_end, stream);
    hipMemsetAsync(d_out, 0, (size_t)B * NS * COUT * 4, stream);

    k_transpose<<<(576 * 128 + 64 * 128 + 255) / 256, 256, 0, stream>>>(conv_w, skip_w, wT, swt);
    k_pix_cnt<<<(B * N0 + 255) / 256, 256, 0, stream>>>(loc, pixf, cnt);
    k_token2map<<<(B * N0 * 64) / 256, 256, 0, stream>>>(x, idx_agg, pixf, cnt, xmap);
    k_conv<<<dim3(7, 56, 8), 128, 0, stream>>>(xmap, wT, conv_b, zpad, conv_out);
    k_wsum<<<(B * N0 + 255) / 256, 256, 0, stream>>>(idx_agg, aggw, wsum);
    k_skip<<<(B * N * 128) / 256, 256, 0, stream>>>(x, swt, xnew);
    k_map2token<<<(B * N0 * 128) / 256, 256, 0, stream>>>(loc, idx_agg, aggw, wsum, conv_out, xnew);
    k_sqn<<<(B * N) / 4, 256, 0, stream>>>(xnew, sqn);

    size_t avail = ws_size > o_d2 ? ws_size - o_d2 : 0;
    int CB = (int)(avail / D2B);
    if (CB > B) CB = B;
    if (CB >= 1) {
        for (int b0 = 0; b0 < B; b0 += CB) {
            int nb = (B - b0 < CB) ? (B - b0) : CB;
            k_d2gemm<<<dim3(49, 49, nb), 256, 0, stream>>>(xnew, sqn, d2, b0);
            k_fps7<<<nb, 256, 0, stream>>>(d2, idx_t, normw, b0);
        }
    } else {
        k_fps0<<<B, 1024, 0, stream>>>(xnew, sqn, idx_t, normw, 0);
    }

    k_merge_scatter<<<(B * N * 128) / 256, 256, 0, stream>>>(xnew, idx_t, normw, out0);
    k_out12<<<(B * N0) / 256, 256, 0, stream>>>(idx_agg, aggw, idx_t, normw, out1, out2, maxw);
    k_out2div<<<(B * N0 + 255) / 256, 256, 0, stream>>>(out2, maxw);
}

// Round 9
// 1997.986 us; speedup vs baseline: 1.1231x; 1.1231x over previous
//
#include <hip/hip_runtime.h>
#include <cstdint>

#define EPSF 1e-6f

// ---------------- problem constants (fixed by setup_inputs) ----------------
constexpr int B = 8, N = 3136, N0 = 12544, CIN = 64, COUT = 128;
constexpr int H = 112, W = 112, HW = H * W;
constexpr int HO = 56, WO = 56, OHW = HO * WO;
constexpr int NS = 784;

// ---------------- workspace layout (bytes) ----------------
constexpr size_t o_xmap = 0;
constexpr size_t sz_xmap = (size_t)B * HW * CIN * 4;
constexpr size_t o_cnt  = o_xmap + sz_xmap;
constexpr size_t sz_cnt = (size_t)B * HW * 4;
constexpr size_t o_wsum = o_cnt + sz_cnt;
constexpr size_t sz_wsum = (size_t)B * N * 4;
constexpr size_t o_maxw = o_wsum + sz_wsum;
constexpr size_t sz_maxw = 32;
constexpr size_t o_zpad = o_maxw + sz_maxw;
constexpr size_t sz_zpad = 256;
constexpr size_t zero_end = o_zpad + sz_zpad;
constexpr size_t o_wt   = (zero_end + 255) & ~(size_t)255;
constexpr size_t o_swt  = o_wt + 576 * 128 * 4;
constexpr size_t o_pixf = o_swt + 64 * 128 * 4;
constexpr size_t o_conv = o_pixf + (size_t)B * N0 * 4;
constexpr size_t o_xnew = o_conv + (size_t)B * OHW * 128 * 4;
constexpr size_t o_sqn  = o_xnew + (size_t)B * N * 128 * 4;
constexpr size_t o_normw = o_sqn + (size_t)B * N * 4;
constexpr size_t o_idxt = o_normw + (size_t)B * N * 4;
constexpr size_t o_d2   = (o_idxt + (size_t)B * N * 4 + 255) & ~(size_t)255;
constexpr size_t D2B = (size_t)N * N * 4;

// order-isomorphic float->uint key: a<b (float) <=> tkey(a)<tkey(b) (uint)
__device__ inline unsigned tkey(float v) {
    unsigned u = __float_as_uint(v);
    unsigned m = (unsigned)((int)u >> 31);
    return u ^ (m | 0x80000000u);
}

// ---------------- weight transpose ----------------
__global__ void k_transpose(const float* __restrict__ conv_w, const float* __restrict__ skip_w,
                            float* __restrict__ wT, float* __restrict__ swt) {
    int g = blockIdx.x * 256 + threadIdx.x;
    if (g < 576 * 128) {
        int k = g >> 7, co = g & 127;
        int kpos = k >> 6, ci = k & 63;
        wT[g] = conv_w[(co * 64 + ci) * 9 + kpos];
    } else {
        int g2 = g - 576 * 128;
        if (g2 < 64 * 128) {
            int ci = g2 >> 7, co = g2 & 127;
            swt[g2] = skip_w[co * 64 + ci];
        }
    }
}

// ---------------- pixel index @112 + count ----------------
__global__ void k_pix_cnt(const float* __restrict__ loc, int* __restrict__ pixf,
                          float* __restrict__ cnt) {
    int g = blockIdx.x * 256 + threadIdx.x;
    if (g >= B * N0) return;
    int b = g / N0;
    float lx = loc[2 * g], ly = loc[2 * g + 1];
    lx = fminf(fmaxf(lx, -1.f), 1.f);
    ly = fminf(fmaxf(ly, -1.f), 1.f);
    int px = (int)rintf((lx + 1.f) * 0.5f * 111.f); px = min(max(px, 0), 111);
    int py = (int)rintf((ly + 1.f) * 0.5f * 111.f); py = min(max(py, 0), 111);
    int pf = b * HW + py * W + px;
    pixf[g] = pf;
    atomicAdd(&cnt[pf], 1.f);
}

// ---------------- token2map scatter ----------------
__global__ void k_token2map(const float* __restrict__ x, const int* __restrict__ idx_agg,
                            const int* __restrict__ pixf, const float* __restrict__ cnt,
                            float* __restrict__ xmap) {
    int t = blockIdx.x * 256 + threadIdx.x;
    int g = t >> 6, c = t & 63;
    if (g >= B * N0) return;
    int pf = pixf[g];
    float val = 1.f / (cnt[pf] + EPSF);
    int b = g / N0;
    int tok = idx_agg[g];
    float xv = x[((size_t)(b * N + tok)) * 64 + c];
    atomicAdd(&xmap[(size_t)pf * 64 + c], xv * val);
}

// ---------------- 3x3 stride-2 conv (NHWC, direct) ----------------
__global__ __launch_bounds__(128) void k_conv(const float* __restrict__ xmap,
                                              const float* __restrict__ wT,
                                              const float* __restrict__ cb,
                                              const float* __restrict__ zpad,
                                              float* __restrict__ conv_out) {
    int co = threadIdx.x;
    int wo0 = blockIdx.x * 8, ho = blockIdx.y, b = blockIdx.z;
    float acc[8];
    float bias = cb[co];
#pragma unroll
    for (int p = 0; p < 8; p++) acc[p] = bias;
    for (int kh = 0; kh < 3; ++kh) {
        int iy = 2 * ho + kh - 1;
        bool vy = (iy >= 0 && iy < H);
        for (int kw = 0; kw < 3; ++kw) {
            const float* wp = wT + (size_t)((kh * 3 + kw) * 64) * 128 + co;
            const float* bp[8];
#pragma unroll
            for (int p = 0; p < 8; p++) {
                int ix = 2 * (wo0 + p) + kw - 1;
                bool v = vy && ix >= 0 && ix < W;
                bp[p] = v ? (xmap + ((size_t)b * HW + iy * W + ix) * 64) : zpad;
            }
#pragma unroll 4
            for (int ci = 0; ci < 64; ++ci) {
                float wv = wp[(size_t)ci * 128];
#pragma unroll
                for (int p = 0; p < 8; p++) acc[p] = fmaf(bp[p][ci], wv, acc[p]);
            }
        }
    }
    size_t ob = ((size_t)b * OHW + ho * WO + wo0) * 128 + co;
#pragma unroll
    for (int p = 0; p < 8; p++) conv_out[ob + (size_t)p * 128] = acc[p];
}

// ---------------- wsum scatter ----------------
__global__ void k_wsum(const int* __restrict__ idx_agg, const float* __restrict__ aggw,
                       float* __restrict__ wsum) {
    int g = blockIdx.x * 256 + threadIdx.x;
    if (g >= B * N0) return;
    int b = g / N0;
    atomicAdd(&wsum[(size_t)b * N + idx_agg[g]], aggw[g]);
}

// ---------------- skip GEMM ----------------
__global__ void k_skip(const float* __restrict__ x, const float* __restrict__ swt,
                       float* __restrict__ xnew) {
    int t = blockIdx.x * 256 + threadIdx.x;
    int g = t >> 7, co = t & 127;
    const float* xr = x + (size_t)g * 64;
    float acc = 0.f;
#pragma unroll 8
    for (int ci = 0; ci < 64; ++ci) acc = fmaf(xr[ci], swt[ci * 128 + co], acc);
    xnew[t] = acc;
}

// ---------------- map2token scatter ----------------
__global__ void k_map2token(const float* __restrict__ loc, const int* __restrict__ idx_agg,
                            const float* __restrict__ aggw, const float* __restrict__ wsum,
                            const float* __restrict__ conv_out, float* __restrict__ xnew) {
    int t = blockIdx.x * 256 + threadIdx.x;
    int g = t >> 7, co = t & 127;
    if (g >= B * N0) return;
    int b = g / N0;
    float lx = loc[2 * g], ly = loc[2 * g + 1];
    lx = fminf(fmaxf(lx, -1.f), 1.f);
    ly = fminf(fmaxf(ly, -1.f), 1.f);
    int px = (int)rintf((lx + 1.f) * 0.5f * 55.f); px = min(max(px, 0), 55);
    int py = (int)rintf((ly + 1.f) * 0.5f * 55.f); py = min(max(py, 0), 55);
    int opix = py * WO + px;
    int tok = idx_agg[g];
    float val = aggw[g] / (wsum[(size_t)b * N + tok] + EPSF);
    float feat = conv_out[((size_t)b * OHW + opix) * 128 + co];
    atomicAdd(&xnew[((size_t)b * N + tok) * 128 + co], feat * val);
}

// ---------------- squared norms ----------------
__global__ void k_sqn(const float* __restrict__ xnew, float* __restrict__ sqn) {
    int tid = threadIdx.x;
    int wid = tid >> 6, lane = tid & 63;
    int row = blockIdx.x * 4 + wid;
    const float* xr = xnew + (size_t)row * 128;
    float2 v = *(const float2*)(xr + lane * 2);
    float s = v.x * v.x + v.y * v.y;
#pragma unroll
    for (int off = 32; off > 0; off >>= 1) s += __shfl_xor(s, off, 64);
    if (lane == 0) sqn[row] = s;
}

// ---------------- D2 GEMM (symmetric): compute by<=bx tiles, mirror-store ----------------
// D2[i][j] == D2[j][i] bit-exactly: fmaf chain is arg-symmetric, sqa+sb-2acc commutes.
__global__ __launch_bounds__(256) void k_d2gemm(const float* __restrict__ xnew,
                                                const float* __restrict__ sqn,
                                                unsigned* __restrict__ d2, int b_off) {
    int bx = blockIdx.x, by = blockIdx.y, cb = blockIdx.z;
    if (by > bx) return;   // lower-triangle tiles produced by mirror store
    __shared__ float As[64 * 132];
    __shared__ float Bs[64 * 132];
    int tid = threadIdx.x;
    int tx = tid & 15, ty = tid >> 4;
    int b = b_off + cb;
    int ri0 = by * 64, rj0 = bx * 64;
    const float* xb = xnew + (size_t)b * N * 128;
#pragma unroll
    for (int q = 0; q < 8; q++) {
        int f4 = tid + q * 256;
        int r = f4 >> 5, k4 = (f4 & 31) << 2;
        *(float4*)&As[r * 132 + k4] = *(const float4*)(xb + (size_t)(ri0 + r) * 128 + k4);
        *(float4*)&Bs[r * 132 + k4] = *(const float4*)(xb + (size_t)(rj0 + r) * 128 + k4);
    }
    __syncthreads();
    float acc[4][4] = {};
    const float* Ap = As + (ty * 4) * 132;
    const float* Bp = Bs + (tx * 4) * 132;
    for (int kk = 0; kk < 32; ++kk) {
        int k = kk * 4;
        float4 a[4], bb[4];
#pragma unroll
        for (int u = 0; u < 4; u++) a[u] = *(const float4*)(Ap + u * 132 + k);
#pragma unroll
        for (int v = 0; v < 4; v++) bb[v] = *(const float4*)(Bp + v * 132 + k);
#pragma unroll
        for (int u = 0; u < 4; u++)
#pragma unroll
            for (int v = 0; v < 4; v++) {
                acc[u][v] = fmaf(a[u].x, bb[v].x, acc[u][v]);
                acc[u][v] = fmaf(a[u].y, bb[v].y, acc[u][v]);
                acc[u][v] = fmaf(a[u].z, bb[v].z, acc[u][v]);
                acc[u][v] = fmaf(a[u].w, bb[v].w, acc[u][v]);
            }
    }
    const float* sq = sqn + (size_t)b * N;
    float4 sb = *(const float4*)(sq + rj0 + tx * 4);
    unsigned* d2c = d2 + (size_t)cb * N * N;
    unsigned okey[4][4];
#pragma unroll
    for (int u = 0; u < 4; u++) {
        int rowg = ri0 + ty * 4 + u;
        float sqa = sq[rowg];
        uint4 o;
        o.x = tkey(sqa + sb.x - 2.f * acc[u][0]);
        o.y = tkey(sqa + sb.y - 2.f * acc[u][1]);
        o.z = tkey(sqa + sb.z - 2.f * acc[u][2]);
        o.w = tkey(sqa + sb.w - 2.f * acc[u][3]);
        okey[u][0] = o.x; okey[u][1] = o.y; okey[u][2] = o.z; okey[u][3] = o.w;
        *(uint4*)(d2c + (size_t)rowg * N + rj0 + tx * 4) = o;
    }
    if (bx != by) {
        // mirror tile: row' = rj0+tx*4+v, cols' = ri0+ty*4+(0..3) -> one uint4 per v
#pragma unroll
        for (int v = 0; v < 4; v++) {
            int colg = rj0 + tx * 4 + v;
            uint4 m = make_uint4(okey[0][v], okey[1][v], okey[2][v], okey[3][v]);
            *(uint4*)(d2c + (size_t)colg * N + ri0 + ty * 4) = m;
        }
    }
}

// ---------------- u64 helpers ----------------
template <int CTRL, int RMASK>
__device__ __forceinline__ unsigned long long dppmax64(unsigned long long k) {
    unsigned lo = (unsigned)k, hi = (unsigned)(k >> 32);
    unsigned slo = (unsigned)__builtin_amdgcn_update_dpp((int)lo, (int)lo, CTRL, RMASK, 0xF, false);
    unsigned shi = (unsigned)__builtin_amdgcn_update_dpp((int)hi, (int)hi, CTRL, RMASK, 0xF, false);
    unsigned long long o = ((unsigned long long)shi << 32) | slo;
    return o > k ? o : k;
}
__device__ __forceinline__ unsigned long long rdlane64(unsigned long long k, int l) {
    unsigned lo = (unsigned)__builtin_amdgcn_readlane((int)(unsigned)k, l);
    unsigned hi = (unsigned)__builtin_amdgcn_readlane((int)(k >> 32), l);
    return ((unsigned long long)hi << 32) | lo;
}

// ---------------- FPS v8 (== measured-best fps6): 256 thr, DPP wave-max, raw barrier ----------------
__global__ __launch_bounds__(256) void k_fps8(const unsigned* __restrict__ d2,
                                              int* __restrict__ idx_t,
                                              float* __restrict__ normw, int b_off) {
    int tid = threadIdx.x;
    int lane = tid & 63, wid = tid >> 6;
    int b = b_off + blockIdx.x;
    const unsigned* D2b = d2 + (size_t)blockIdx.x * (size_t)N * N;
    __shared__ unsigned long long slot[2][4];
    __shared__ int cent_l[NS];
    __shared__ int it_l[N];
    __shared__ float cntw[NS];
    const bool full = (tid < 16);       // r=3 tail: elems 3072..3135 owned by tid 0..15
    const unsigned KI = tkey(1e10f);
    unsigned kd[16];
    int am[16];
#pragma unroll
    for (int r = 0; r < 4; r++)
#pragma unroll
        for (int c = 0; c < 4; c++) { kd[r * 4 + c] = (r < 3 || full) ? KI : 0u; am[r * 4 + c] = 0; }

    int far = 0;
    for (int s = 0; s < NS; ++s) {
        if (tid == 0) cent_l[s] = far;
        // row load (16 elems/thread, 4x dwordx4)
        const unsigned* row = D2b + (size_t)far * N;
        uint4 v0 = *(const uint4*)(row + tid * 4);
        uint4 v1 = *(const uint4*)(row + 1024 + tid * 4);
        uint4 v2 = *(const uint4*)(row + 2048 + tid * 4);
        uint4 v3 = full ? *(const uint4*)(row + 3072 + tid * 4) : make_uint4(0, 0, 0, 0);
        // min-update + merge argmin (strict < -> first-s wins ties)
        uint4 vv[4] = {v0, v1, v2, v3};
#pragma unroll
        for (int r = 0; r < 4; r++) {
            unsigned e[4] = {vv[r].x, vv[r].y, vv[r].z, vv[r].w};
#pragma unroll
            for (int c = 0; c < 4; c++)
                if (e[c] < kd[r * 4 + c]) { kd[r * 4 + c] = e[c]; am[r * 4 + c] = s; }
        }
        if (s == NS - 1) break;   // last row updates assignments only (no next-far needed)
        // per-thread max of kd
        unsigned tmax = kd[0];
#pragma unroll
        for (int q = 1; q < 16; q++) tmax = max(tmax, kd[q]);
        // per-thread smallest global index achieving tmax
        unsigned il = 4095u;
#pragma unroll
        for (int r = 3; r >= 0; --r)
#pragma unroll
            for (int c = 3; c >= 0; --c)
                if (kd[r * 4 + c] == tmax) il = (unsigned)(r * 1024 + tid * 4 + c);
        unsigned long long key = ((unsigned long long)tmax << 12) | (unsigned long long)(4095u - il);
        // wave max via DPP (pure VALU)
        key = dppmax64<0xB1, 0xF>(key);    // quad_perm [1,0,3,2]
        key = dppmax64<0x4E, 0xF>(key);    // quad_perm [2,3,0,1]
        key = dppmax64<0x141, 0xF>(key);   // row_half_mirror
        key = dppmax64<0x140, 0xF>(key);   // row_mirror  -> each 16-row has its max
        key = dppmax64<0x142, 0xA>(key);   // row_bcast15 -> rows 1,3
        key = dppmax64<0x143, 0xC>(key);   // row_bcast31 -> rows 2,3 ; lane63 = wave max
        unsigned long long wmax = rdlane64(key, 63);   // wave-uniform
        int cur = s & 1;
        if (lane == 0) slot[cur][wid] = wmax;
        // raw barrier: LDS visibility only (no vmcnt drain; loads already consumed)
        asm volatile("s_waitcnt lgkmcnt(0)\n\ts_barrier" ::: "memory");
        unsigned long long s0 = slot[cur][0], s1 = slot[cur][1];
        unsigned long long s2 = slot[cur][2], s3 = slot[cur][3];
        unsigned long long m0 = s0 > s1 ? s0 : s1;
        unsigned long long m1 = s2 > s3 ? s2 : s3;
        unsigned long long win = m0 > m1 ? m0 : m1;
        far = 4095 - (int)(win & 0xFFFull);
    }
    // ---------------- epilogue ----------------
    __syncthreads();
#pragma unroll
    for (int r = 0; r < 4; r++) {
        if (r == 3 && !full) break;
        int i0 = r * 1024 + tid * 4;
        *(int4*)&it_l[i0] = make_int4(am[r * 4 + 0], am[r * 4 + 1], am[r * 4 + 2], am[r * 4 + 3]);
    }
    for (int t = tid; t < NS; t += 256) cntw[t] = 0.f;
    __syncthreads();
    for (int t = tid; t < NS; t += 256) it_l[cent_l[t]] = t;   // centroid -> itself
    __syncthreads();
    for (int i = tid; i < N; i += 256) atomicAdd(&cntw[it_l[i]], 1.f);
    __syncthreads();
    int* it = idx_t + (size_t)b * N;
    float* nw = normw + (size_t)b * N;
    for (int i = tid; i < N; i += 256) {
        int t = it_l[i];
        it[i] = t;
        nw[i] = 1.f / (cntw[t] + EPSF);
    }
}

// ---------------- fallback FPS (no-D2 path) ----------------
__device__ inline unsigned long long packkey(float v, unsigned i) {
    unsigned u = __float_as_uint(v);
    u = (u & 0x80000000u) ? ~u : (u | 0x80000000u);
    return ((unsigned long long)u << 32) | (unsigned long long)(0xFFFFFFFFu - i);
}

__global__ __launch_bounds__(1024) void k_fps0(const float* __restrict__ xnew,
                                               const float* __restrict__ sqn,
                                               int* __restrict__ idx_t,
                                               float* __restrict__ normw, int b_off) {
    int tid = threadIdx.x;
    int b = b_off + blockIdx.x;
    __shared__ unsigned long long slot[2];
    __shared__ int cent[NS];
    __shared__ float cntw[NS];
    __shared__ float csh[128];
    if (tid == 0) { slot[0] = 0ull; slot[1] = 0ull; }
    if (tid < NS) cntw[tid] = 0.f;
    float dist[4] = {1e10f, 1e10f, 1e10f, 1e10f};
    int amin[4] = {0, 0, 0, 0};
    float sqi[4];
#pragma unroll
    for (int r = 0; r < 4; r++) {
        int i = tid + r * 1024;
        if (i < N) sqi[r] = sqn[(size_t)b * N + i];
    }
    __syncthreads();
    int far = 0;
    for (int s = 0; s < NS; ++s) {
        int cur = s & 1;
        if (tid == 0) { cent[s] = far; slot[cur ^ 1] = 0ull; }
        if (tid < 128) csh[tid] = xnew[((size_t)b * N + far) * 128 + tid];
        float sqf = sqn[(size_t)b * N + far];
        __syncthreads();
        unsigned long long key = 0ull;
#pragma unroll
        for (int r = 0; r < 4; r++) {
            int i = tid + r * 1024;
            if (i < N) {
                const float* xr = xnew + ((size_t)b * N + i) * 128;
                float dot = 0.f;
#pragma unroll 8
                for (int k = 0; k < 128; k++) dot = fmaf(xr[k], csh[k], dot);
                float d = sqi[r] + sqf - 2.f * dot;
                if (d < dist[r]) { dist[r] = d; amin[r] = s; }
                unsigned long long k2 = packkey(dist[r], (unsigned)i);
                if (k2 > key) key = k2;
            }
        }
#pragma unroll
        for (int off = 32; off > 0; off >>= 1) {
            unsigned long long o = __shfl_xor(key, off, 64);
            if (o > key) key = o;
        }
        if ((tid & 63) == 0) atomicMax(&slot[cur], key);
        __syncthreads();
        unsigned long long kk = slot[cur];
        far = (int)(0xFFFFFFFFu - (unsigned)(kk & 0xFFFFFFFFull));
        __syncthreads();
    }
    int* it = idx_t + (size_t)b * N;
#pragma unroll
    for (int r = 0; r < 4; r++) { int i = tid + r * 1024; if (i < N) it[i] = amin[r]; }
    __syncthreads();
    if (tid < NS) it[cent[tid]] = tid;
    __syncthreads();
#pragma unroll
    for (int r = 0; r < 4; r++) { int i = tid + r * 1024; if (i < N) atomicAdd(&cntw[it[i]], 1.f); }
    __syncthreads();
    float* nw = normw + (size_t)b * N;
#pragma unroll
    for (int r = 0; r < 4; r++) {
        int i = tid + r * 1024;
        if (i < N) nw[i] = 1.f / (cntw[it[i]] + EPSF);
    }
}

// ---------------- merged-token scatter into out0 ----------------
__global__ void k_merge_scatter(const float* __restrict__ xnew, const int* __restrict__ idx_t,
                                const float* __restrict__ normw, float* __restrict__ out0) {
    int t = blockIdx.x * 256 + threadIdx.x;
    int g = t >> 7, co = t & 127;
    if (g >= B * N) return;
    int b = g / N;
    int s = idx_t[g];
    float nwv = normw[g];
    atomicAdd(&out0[((size_t)b * NS + s) * 128 + co], xnew[(size_t)g * 128 + co] * nwv);
}

// ---------------- outputs 1 & 2 (hierarchical max) ----------------
__global__ void k_out12(const int* __restrict__ idx_agg, const float* __restrict__ aggw,
                        const int* __restrict__ idx_t, const float* __restrict__ normw,
                        float* __restrict__ out1, float* __restrict__ out2,
                        unsigned* __restrict__ maxw) {
    int tid = threadIdx.x;
    int q = blockIdx.x * 256 + tid;
    int b = q / N0;
    int tok = idx_agg[q];
    int it = idx_t[(size_t)b * N + tok];
    out1[q] = (float)it;
    float aw = aggw[q] * normw[(size_t)b * N + tok];
    out2[q] = aw;
    float m = aw;
#pragma unroll
    for (int off = 32; off > 0; off >>= 1) m = fmaxf(m, __shfl_xor(m, off, 64));
    __shared__ float wmax[4];
    int lane = tid & 63, wid = tid >> 6;
    if (lane == 0) wmax[wid] = m;
    __syncthreads();
    if (tid == 0) {
        float mm = fmaxf(fmaxf(wmax[0], wmax[1]), fmaxf(wmax[2], wmax[3]));
        atomicMax(&maxw[b], __float_as_uint(mm));
    }
}

__global__ void k_out2div(float* __restrict__ out2, const unsigned* __restrict__ maxw) {
    int q = blockIdx.x * 256 + threadIdx.x;
    if (q >= B * N0) return;
    int b = q / N0;
    out2[q] = out2[q] / __uint_as_float(maxw[b]);
}

// ---------------- launcher ----------------
extern "C" void kernel_launch(void* const* d_in, const int* in_sizes, int n_in,
                              void* d_out, int out_size, void* d_ws, size_t ws_size,
                              hipStream_t stream) {
    const float* x = (const float*)d_in[0];
    const float* loc = (const float*)d_in[1];
    const int* idx_agg = (const int*)d_in[2];
    const float* aggw = (const float*)d_in[3];
    const float* conv_w = (const float*)d_in[4];
    const float* conv_b = (const float*)d_in[5];
    const float* skip_w = (const float*)d_in[6];

    char* ws = (char*)d_ws;
    float* xmap = (float*)(ws + o_xmap);
    float* cnt = (float*)(ws + o_cnt);
    float* wsum = (float*)(ws + o_wsum);
    unsigned* maxw = (unsigned*)(ws + o_maxw);
    float* zpad = (float*)(ws + o_zpad);
    float* wT = (float*)(ws + o_wt);
    float* swt = (float*)(ws + o_swt);
    int* pixf = (int*)(ws + o_pixf);
    float* conv_out = (float*)(ws + o_conv);
    float* xnew = (float*)(ws + o_xnew);
    float* sqn = (float*)(ws + o_sqn);
    float* normw = (float*)(ws + o_normw);
    int* idx_t = (int*)(ws + o_idxt);
    unsigned* d2 = (unsigned*)(ws + o_d2);

    float* out0 = (float*)d_out;
    float* out1 = out0 + (size_t)B * NS * COUT;
    float* out2 = out1 + (size_t)B * N0;

    hipMemsetAsync(d_ws, 0, zero_end, stream);
    hipMemsetAsync(d_out, 0, (size_t)B * NS * COUT * 4, stream);

    k_transpose<<<(576 * 128 + 64 * 128 + 255) / 256, 256, 0, stream>>>(conv_w, skip_w, wT, swt);
    k_pix_cnt<<<(B * N0 + 255) / 256, 256, 0, stream>>>(loc, pixf, cnt);
    k_token2map<<<(B * N0 * 64) / 256, 256, 0, stream>>>(x, idx_agg, pixf, cnt, xmap);
    k_conv<<<dim3(7, 56, 8), 128, 0, stream>>>(xmap, wT, conv_b, zpad, conv_out);
    k_wsum<<<(B * N0 + 255) / 256, 256, 0, stream>>>(idx_agg, aggw, wsum);
    k_skip<<<(B * N * 128) / 256, 256, 0, stream>>>(x, swt, xnew);
    k_map2token<<<(B * N0 * 128) / 256, 256, 0, stream>>>(loc, idx_agg, aggw, wsum, conv_out, xnew);
    k_sqn<<<(B * N) / 4, 256, 0, stream>>>(xnew, sqn);

    size_t avail = ws_size > o_d2 ? ws_size - o_d2 : 0;
    int CB = (int)(avail / D2B);
    if (CB > B) CB = B;
    if (CB >= 1) {
        for (int b0 = 0; b0 < B; b0 += CB) {
            int nb = (B - b0 < CB) ? (B - b0) : CB;
            k_d2gemm<<<dim3(49, 49, nb), 256, 0, stream>>>(xnew, sqn, d2, b0);
            k_fps8<<<nb, 256, 0, stream>>>(d2, idx_t, normw, b0);
        }
    } else {
        k_fps0<<<B, 1024, 0, stream>>>(xnew, sqn, idx_t, normw, 0);
    }

    k_merge_scatter<<<(B * N * 128) / 256, 256, 0, stream>>>(xnew, idx_t, normw, out0);
    k_out12<<<(B * N0) / 256, 256, 0, stream>>>(idx_agg, aggw, idx_t, normw, out1, out2, maxw);
    k_out2div<<<(B * N0 + 255) / 256, 256, 0, stream>>>(out2, maxw);
}